// Round 1
// baseline (263.564 us; speedup 1.0000x reference)
//
#include <hip/hip_runtime.h>

using bf16x8 = __attribute__((ext_vector_type(8))) short;
using f32x4  = __attribute__((ext_vector_type(4))) float;
using u32x4  = __attribute__((ext_vector_type(4))) unsigned int;

__device__ __forceinline__ unsigned short f2bf(float f) {
  unsigned int u = __builtin_bit_cast(unsigned int, f);
  u += 0x7FFF + ((u >> 16) & 1);               // RNE
  return (unsigned short)(u >> 16);
}
__device__ __forceinline__ bf16x8 lds_frag(const unsigned short* p) {
  return __builtin_bit_cast(bf16x8, *(const u32x4*)p);
}
// async global->LDS, 16B per lane; LDS dest = wave-uniform base + lane*16
__device__ __forceinline__ void async_copy16(const unsigned short* g, unsigned short* l) {
  __builtin_amdgcn_global_load_lds(
      (const __attribute__((address_space(1))) unsigned int*)g,
      (__attribute__((address_space(3))) unsigned int*)l, 16, 0, 0);
}

// fp32 -> bf16 elementwise, 8 elems/thread
__global__ void cast_bf16_k(const float* __restrict__ in,
                            unsigned short* __restrict__ out, int n) {
  int i = (blockIdx.x * 256 + threadIdx.x) * 8;
  if (i < n) {
    unsigned short r[8];
    #pragma unroll
    for (int j = 0; j < 8; ++j) r[j] = f2bf(in[i + j]);
    *(u32x4*)&out[i] = *(u32x4*)r;
  }
}

// LDS-tiled transpose+cast: out[c*R+r] = bf16(in[r*C+c]). R,C multiples of 32.
__global__ void transpose_cast_k(const float* __restrict__ in,
                                 unsigned short* __restrict__ out, int R, int C) {
  __shared__ float tile[32][33];
  const int tx = threadIdx.x & 31, ty = threadIdx.x >> 5;   // 32 x 8
  const int c0 = blockIdx.x * 32, r0 = blockIdx.y * 32;
  #pragma unroll
  for (int i = 0; i < 4; ++i)
    tile[ty + i * 8][tx] = in[(size_t)(r0 + ty + i * 8) * C + c0 + tx];
  __syncthreads();
  #pragma unroll
  for (int i = 0; i < 4; ++i)
    out[(size_t)(c0 + ty + i * 8) * R + r0 + tx] = f2bf(tile[tx][ty + i * 8]);
}

// One quadrant phase: 4 A-frags (m-half MH, k-slice KS) x 4 B-frags -> 16 MFMA.
// B-frags are (re)loaded only when KS changes (LDB). Ends with a raw barrier.
template <int MH, int KS, bool LDB>
__device__ __forceinline__ void qphase(const unsigned short* __restrict__ As,
                                       const unsigned short* __restrict__ Bs,
                                       f32x4 (&acc)[8][4], bf16x8 (&bfr)[4],
                                       int arow, int brow, int quad, int sx) {
  const int sw = ((KS * 4 + quad) ^ sx) * 8;   // XOR-8 swizzled 16B-group
  bf16x8 af[4];
  #pragma unroll
  for (int m = 0; m < 4; ++m)
    af[m] = lds_frag(&As[(arow + MH * 64 + m * 16) * 64 + sw]);
  if constexpr (LDB) {
    #pragma unroll
    for (int n = 0; n < 4; ++n)
      bfr[n] = lds_frag(&Bs[(brow + n * 16) * 64 + sw]);
  }
  __builtin_amdgcn_s_setprio(1);
  #pragma unroll
  for (int m = 0; m < 4; ++m)
    #pragma unroll
    for (int n = 0; n < 4; ++n)
      acc[MH * 4 + m][n] = __builtin_amdgcn_mfma_f32_16x16x32_bf16(
          af[m], bfr[n], acc[MH * 4 + m][n], 0, 0, 0);
  __builtin_amdgcn_s_setprio(0);
  __builtin_amdgcn_s_barrier();
}

// C[M,N] = A[M,K] @ Bt[N,K]^T (+bias for fp32 out), bf16 in, fp32 accum.
// 256x256 tile, BK=64, 512 threads (8 waves, 2M x 4N), double-buffered LDS,
// 8-phase schedule with counted vmcnt (T3+T4) + setprio (T5).
// Schedule invariants (race-free by construction):
//  - STAGE into a buffer is issued only AFTER the barrier following the last
//    qphase that read it (reads drained via MFMA data-dep before that barrier).
//  - Counted vmcnt(8) forces only the OTHER buffer's 8 loads (issued 4 phases
//    = ~4x16 MFMA earlier) to have landed; s_barrier then publishes to all waves.
template <typename OutT>
__global__ __launch_bounds__(512, 2)
void gemm_bt256(const unsigned short* __restrict__ A,
                const unsigned short* __restrict__ Bt,
                OutT* __restrict__ C,
                const float* __restrict__ bias,
                int M, int N, int K, int n_tiles, int mt_per_xcd) {
  __shared__ unsigned short Ash[2][256 * 64];   // 64 KB
  __shared__ unsigned short Bsh[2][256 * 64];   // 64 KB
  const int tid  = threadIdx.x;                 // 0..511
  const int wv   = tid >> 6, lane = tid & 63;
  const int quad = lane >> 4, l15 = lane & 15;
  const int wr   = wv >> 2, wc = wv & 3;        // 2M x 4N wave grid

  const int b = blockIdx.x;
  const int xcd = b & 7, local = b >> 3;        // grid % 8 == 0 -> bijective
  const int mt = xcd * mt_per_xcd + local / n_tiles;
  const int nt = local % n_tiles;
  const int m0 = mt * 256, n0 = nt * 256;

  // staging: 2048 16B-groups per matrix per K-tile; call p in 0..3, lin=p*512+tid
  // LDS slot lin = (row = lin>>3, gslot = lin&7); global group = gslot ^ (row&7)
  const unsigned short* pA[4];
  const unsigned short* pB[4];
  #pragma unroll
  for (int p = 0; p < 4; ++p) {
    int lin = p * 512 + tid;
    int row = lin >> 3, g = (lin & 7) ^ (row & 7);
    pA[p] = &A[(size_t)(m0 + row) * K + g * 8];
    pB[p] = &Bt[(size_t)(n0 + row) * K + g * 8];
  }

  f32x4 acc[8][4];
  #pragma unroll
  for (int i = 0; i < 8; ++i)
    #pragma unroll
    for (int j = 0; j < 4; ++j)
      acc[i][j] = (f32x4){0.f, 0.f, 0.f, 0.f};

  const int arow = wr * 128 + l15;
  const int brow = wc * 64 + l15;
  const int sx   = l15 & 7;
  bf16x8 bfr[4];

  // prologue: stage K-tile 0 into buffer 0 (one-time full-latency wait at ph0)
  #pragma unroll
  for (int p = 0; p < 4; ++p) async_copy16(pA[p], &Ash[0][(p * 512 + tid) * 8]);
  #pragma unroll
  for (int p = 0; p < 4; ++p) async_copy16(pB[p], &Bsh[0][(p * 512 + tid) * 8]);

  const int niter = K >> 7;                     // K/128, two K-tiles per iter
  for (int it = 0; it < niter; ++it) {
    // ph0 entry: issue buf1 <- K-tile 2it+1, counted wait on buf0, publish
    {
      const int k1 = (2 * it + 1) << 6;
      #pragma unroll
      for (int p = 0; p < 4; ++p) async_copy16(pA[p] + k1, &Ash[1][(p * 512 + tid) * 8]);
      #pragma unroll
      for (int p = 0; p < 4; ++p) async_copy16(pB[p] + k1, &Bsh[1][(p * 512 + tid) * 8]);
    }
    asm volatile("s_waitcnt vmcnt(8)" ::: "memory");
    __builtin_amdgcn_s_barrier();
    // phases 0-3: compute buf0 (K-tile 2it)
    qphase<0, 0, true >(Ash[0], Bsh[0], acc, bfr, arow, brow, quad, sx);
    qphase<1, 0, false>(Ash[0], Bsh[0], acc, bfr, arow, brow, quad, sx);
    qphase<0, 1, true >(Ash[0], Bsh[0], acc, bfr, arow, brow, quad, sx);
    qphase<1, 1, false>(Ash[0], Bsh[0], acc, bfr, arow, brow, quad, sx);
    // ph4 entry: issue buf0 <- K-tile 2it+2 (if any), counted wait on buf1
    if (it + 1 < niter) {
      const int k2 = (2 * it + 2) << 6;
      #pragma unroll
      for (int p = 0; p < 4; ++p) async_copy16(pA[p] + k2, &Ash[0][(p * 512 + tid) * 8]);
      #pragma unroll
      for (int p = 0; p < 4; ++p) async_copy16(pB[p] + k2, &Bsh[0][(p * 512 + tid) * 8]);
      asm volatile("s_waitcnt vmcnt(8)" ::: "memory");
    } else {
      asm volatile("s_waitcnt vmcnt(0)" ::: "memory");
    }
    __builtin_amdgcn_s_barrier();
    // phases 4-7: compute buf1 (K-tile 2it+1)
    qphase<0, 0, true >(Ash[1], Bsh[1], acc, bfr, arow, brow, quad, sx);
    qphase<1, 0, false>(Ash[1], Bsh[1], acc, bfr, arow, brow, quad, sx);
    qphase<0, 1, true >(Ash[1], Bsh[1], acc, bfr, arow, brow, quad, sx);
    qphase<1, 1, false>(Ash[1], Bsh[1], acc, bfr, arow, brow, quad, sx);
  }

  #pragma unroll
  for (int mf = 0; mf < 8; ++mf) {
    #pragma unroll
    for (int n = 0; n < 4; ++n) {
      int col = n0 + wc * 64 + n * 16 + l15;
      float badd = (bias != nullptr) ? bias[col] : 0.f;
      #pragma unroll
      for (int r = 0; r < 4; ++r) {
        int row = m0 + wr * 128 + mf * 16 + quad * 4 + r;
        if constexpr (sizeof(OutT) == 2)
          C[(size_t)row * N + col] = f2bf(acc[mf][n][r] + badd);
        else
          C[(size_t)row * N + col] = acc[mf][n][r] + badd;
      }
    }
  }
}

// Local attention: one block per (head, window). qkv: 16384 x 1536 bf16,
// out: 16384 x 512 bf16. WSZ=128, lookback window of 128 (zeros for w==0).
// mask: col <= row + 128. scale = 1/8.
__global__ __launch_bounds__(256, 2)
void attn_local(const unsigned short* __restrict__ qkv,
                unsigned short* __restrict__ out) {
  // Ksh: [ks(2)][j(256)][32] (64B rows -> b128 frags). Psh overlays Ksh.
  // VshT: V^T col-major [n(64)][k(256)], XOR swizzle: 16B-group g of row n at
  // slot g^(n&7) -> both staging stores and PV frag reads are conflict-optimal.
  __shared__ unsigned short Ksh[2 * 256 * 32];   // 32 KB
  __shared__ unsigned short VshT[64 * 256];      // 32 KB
  unsigned short* Psh = Ksh;

  const int tid  = threadIdx.x;
  const int wv   = tid >> 6, lane = tid & 63;
  const int quad = lane >> 4, l15 = lane & 15;
  const int h = blockIdx.x & 7, w = blockIdx.x >> 3;

  // stage K (k-tiled); rows j<128 of window 0 are zeros
  #pragma unroll
  for (int p = 0; p < 8; ++p) {
    int c = p * 256 + tid;                 // 2048 = 256 rows x 8 vec8-groups
    int j = c >> 3, sub = c & 7;
    u32x4 kvv = (u32x4){0, 0, 0, 0};
    if (!(w == 0 && j < 128)) {
      size_t base = (size_t)((w - 1) * 128 + j) * 1536 + h * 64 + sub * 8;
      kvv = *(const u32x4*)&qkv[base + 512];
    }
    *(u32x4*)&Ksh[(sub >> 2) * 8192 + j * 32 + (sub & 3) * 8] = kvv;
  }
  // stage V^T: thread (n = tid&63, kb4 = tid>>6) loads column n, 8 k's per iter
  {
    const int n = tid & 63, kb4 = tid >> 6;
    #pragma unroll
    for (int kk = 0; kk < 8; ++kk) {
      int kb = kk * 4 + kb4;               // group 0..31, k0 = kb*8
      unsigned short tmp[8];
      if (w == 0 && kb < 16) {
        #pragma unroll
        for (int j = 0; j < 8; ++j) tmp[j] = 0;
      } else {
        #pragma unroll
        for (int j = 0; j < 8; ++j)
          tmp[j] = qkv[(size_t)((w - 1) * 128 + kb * 8 + j) * 1536 + 1024 + h * 64 + n];
      }
      *(u32x4*)&VshT[n * 256 + ((kb ^ (n & 7)) * 8)] = *(u32x4*)tmp;
    }
  }
  __syncthreads();

  // Q fragments straight from global (A-operand: row l15, k = ks*32+quad*8..+7)
  bf16x8 qf[2][2];
  #pragma unroll
  for (int mt = 0; mt < 2; ++mt) {
    int tok = w * 128 + (wv * 2 + mt) * 16 + l15;
    #pragma unroll
    for (int ks = 0; ks < 2; ++ks)
      qf[mt][ks] = __builtin_bit_cast(
          bf16x8, *(const u32x4*)&qkv[(size_t)tok * 1536 + h * 64 + ks * 32 + quad * 8]);
  }

  // scores: wave wv owns rows [wv*32, wv*32+32) => m-tiles {2wv, 2wv+1}
  float s[2][16][4];
  #pragma unroll
  for (int nt = 0; nt < 16; ++nt) {
    bf16x8 kf0 = lds_frag(&Ksh[0    + (nt * 16 + l15) * 32 + quad * 8]);
    bf16x8 kf1 = lds_frag(&Ksh[8192 + (nt * 16 + l15) * 32 + quad * 8]);
    #pragma unroll
    for (int mt = 0; mt < 2; ++mt) {
      f32x4 a = (f32x4){0.f, 0.f, 0.f, 0.f};
      a = __builtin_amdgcn_mfma_f32_16x16x32_bf16(qf[mt][0], kf0, a, 0, 0, 0);
      a = __builtin_amdgcn_mfma_f32_16x16x32_bf16(qf[mt][1], kf1, a, 0, 0, 0);
      #pragma unroll
      for (int r = 0; r < 4; ++r) s[mt][nt][r] = a[r];
    }
  }

  // masked softmax in registers (row = mtile*16 + quad*4 + r, col = nt*16 + l15)
  #pragma unroll
  for (int mt = 0; mt < 2; ++mt) {
    int rowb = (wv * 2 + mt) * 16 + quad * 4;
    #pragma unroll
    for (int r = 0; r < 4; ++r) {
      int lim = rowb + r + 128;
      float mx = -3.0e38f;
      #pragma unroll
      for (int nt = 0; nt < 16; ++nt) {
        float v = ((nt * 16 + l15) <= lim) ? s[mt][nt][r] * 0.125f : -3.0e38f;
        s[mt][nt][r] = v;
        mx = fmaxf(mx, v);
      }
      mx = fmaxf(mx, __shfl_xor(mx, 1));
      mx = fmaxf(mx, __shfl_xor(mx, 2));
      mx = fmaxf(mx, __shfl_xor(mx, 4));
      mx = fmaxf(mx, __shfl_xor(mx, 8));
      float sum = 0.f;
      #pragma unroll
      for (int nt = 0; nt < 16; ++nt) {
        float p = __expf(s[mt][nt][r] - mx);   // masked -> exp(-huge) = 0
        s[mt][nt][r] = p;
        sum += p;
      }
      sum += __shfl_xor(sum, 1);
      sum += __shfl_xor(sum, 2);
      sum += __shfl_xor(sum, 4);
      sum += __shfl_xor(sum, 8);
      float inv = 1.f / sum;
      #pragma unroll
      for (int nt = 0; nt < 16; ++nt) s[mt][nt][r] *= inv;
    }
  }

  __syncthreads();   // all waves done reading Ksh -> safe to overlay P

  // PV: per m-tile, round-trip P through per-wave LDS region (C-layout -> A-layout)
  #pragma unroll
  for (int mt = 0; mt < 2; ++mt) {
    #pragma unroll
    for (int nt = 0; nt < 16; ++nt)
      #pragma unroll
      for (int r = 0; r < 4; ++r)
        Psh[wv * 4096 + (nt >> 1) * 512 + (quad * 4 + r) * 32 + (nt & 1) * 16 + l15] =
            f2bf(s[mt][nt][r]);
    __syncthreads();
    f32x4 o[4];
    #pragma unroll
    for (int n2 = 0; n2 < 4; ++n2) o[n2] = (f32x4){0.f, 0.f, 0.f, 0.f};
    #pragma unroll
    for (int ks = 0; ks < 8; ++ks) {
      bf16x8 pa = lds_frag(&Psh[wv * 4096 + ks * 512 + l15 * 32 + quad * 8]);
      #pragma unroll
      for (int n2 = 0; n2 < 4; ++n2) {
        bf16x8 vb = lds_frag(&VshT[(n2 * 16 + l15) * 256 + (((ks * 4 + quad) ^ (l15 & 7)) * 8)]);
        o[n2] = __builtin_amdgcn_mfma_f32_16x16x32_bf16(pa, vb, o[n2], 0, 0, 0);
      }
    }
    int tokb = w * 128 + (wv * 2 + mt) * 16 + quad * 4;
    #pragma unroll
    for (int n2 = 0; n2 < 4; ++n2)
      #pragma unroll
      for (int r = 0; r < 4; ++r)
        out[(size_t)(tokb + r) * 512 + h * 64 + n2 * 16 + l15] = f2bf(o[n2][r]);
    __syncthreads();
  }
}

extern "C" void kernel_launch(void* const* d_in, const int* in_sizes, int n_in,
                              void* d_out, int out_size, void* d_ws, size_t ws_size,
                              hipStream_t stream) {
  const float* x     = (const float*)d_in[0];  // 16384 x 1024 fp32
  const float* w_qkv = (const float*)d_in[1];  // 1024 x 1536 fp32
  const float* w_out = (const float*)d_in[2];  // 512 x 1024 fp32
  const float* b_out = (const float*)d_in[3];  // 1024 fp32
  float* out = (float*)d_out;                  // 16384 x 1024 fp32

  char* ws = (char*)d_ws;
  unsigned short* xb    = (unsigned short*)ws;                     // 16384x1024 bf16 (32 MB)
  unsigned short* wqkvT = (unsigned short*)(ws + 33554432);        // 1536x1024 (3 MB)
  unsigned short* woutT = (unsigned short*)(ws + 36700160);        // 1024x512  (1 MB)
  unsigned short* qkv   = (unsigned short*)(ws + 37748736);        // 16384x1536 (48 MB)
  unsigned short* attno = (unsigned short*)(ws + 88080384);        // 16384x512 (16 MB)

  cast_bf16_k<<<8192, 256, 0, stream>>>(x, xb, 16384 * 1024);
  transpose_cast_k<<<dim3(48, 32), 256, 0, stream>>>(w_qkv, wqkvT, 1024, 1536);
  transpose_cast_k<<<dim3(32, 16), 256, 0, stream>>>(w_out, woutT, 512, 1024);
  // QKV: 64 m-tiles x 6 n-tiles (256^2); 8 m-tiles per xcd
  gemm_bt256<unsigned short><<<384, 512, 0, stream>>>(
      xb, wqkvT, qkv, nullptr, 16384, 1536, 1024, 6, 8);
  attn_local<<<1024, 256, 0, stream>>>(qkv, attno);
  // out-proj: 64 m-tiles x 4 n-tiles (256^2); 8 m-tiles per xcd
  gemm_bt256<float><<<256, 512, 0, stream>>>(
      attno, woutT, out, b_out, 16384, 1024, 512, 4, 8);
}